// Round 1
// baseline (31.155 us; speedup 1.0000x reference)
//
#include <hip/hip_runtime.h>
#include <math.h>

#define BATCH 128
#define CHANS 32
#define TLEN 4096
#define LEVELS 4
#define NTAPS 4
#define SLOPE 10.0f

__global__ __launch_bounds__(256) void lwpt_kernel(
    const float* __restrict__ x, const float* __restrict__ h_lo,
    const float* __restrict__ bias, float* __restrict__ out)
{
    __shared__ float buf0[TLEN];
    __shared__ float buf1[TLEN / 2];

    const int bc  = blockIdx.x;          // 0 .. BATCH*CHANS-1  (row index)
    const int c   = bc & (CHANS - 1);    // channel
    const int tid = threadIdx.x;

    // ---- stage input row into LDS, float4-coalesced (4096 floats = 4 x float4/thread)
    const float4* xin = (const float4*)(x + (size_t)bc * TLEN);
    float4* b0v = (float4*)buf0;
    #pragma unroll
    for (int k = 0; k < TLEN / 4 / 256; ++k)
        b0v[tid + k * 256] = xin[tid + k * 256];
    __syncthreads();

    float* src = buf0;
    float* dst = buf1;
    float* orow = out + (size_t)bc * TLEN;

    #pragma unroll
    for (int l = 0; l < LEVELS; ++l) {
        const int Tl = TLEN >> l;        // input length this level
        const int To = Tl >> 1;          // output length (lo and hi each)

        const float k0 = h_lo[(c * LEVELS + l) * NTAPS + 0];
        const float k1 = h_lo[(c * LEVELS + l) * NTAPS + 1];
        const float k2 = h_lo[(c * LEVELS + l) * NTAPS + 2];
        const float k3 = h_lo[(c * LEVELS + l) * NTAPS + 3];
        // k_hi = sign * h_lo reversed = [+k3, -k2, +k1, -k0]
        const float bl = bias[c * LEVELS + l];

        for (int t = tid; t < To; t += 256) {
            const int i0 = 2 * t;
            const float a0 = src[i0];
            const float a1 = src[i0 + 1];
            const float a2 = src[(i0 + 2 >= Tl) ? (i0 + 2 - Tl) : (i0 + 2)];
            const float a3 = src[(i0 + 3 >= Tl) ? (i0 + 3 - Tl) : (i0 + 3)];

            const float lo = a0 * k0 + a1 * k1 + a2 * k2 + a3 * k3;
            const float hi = a0 * k3 - a1 * k2 + a2 * k1 - a3 * k0;

            dst[t] = lo;

            // d = hi * (sigmoid(S*(hi-b)) + sigmoid(-S*(hi+b)))
            const float s1 = 1.0f / (1.0f + __expf(-SLOPE * (hi - bl)));
            const float s2 = 1.0f / (1.0f + __expf( SLOPE * (hi + bl)));
            orow[To + t] = hi * (s1 + s2);   // detail level (l+1): offset == length == To
        }
        __syncthreads();
        float* tmp = src; src = dst; dst = tmp;
    }

    // final approximation coefficients: length TLEN>>LEVELS = 256, sitting in src
    if (tid < (TLEN >> LEVELS))
        orow[tid] = src[tid];
}

extern "C" void kernel_launch(void* const* d_in, const int* in_sizes, int n_in,
                              void* d_out, int out_size, void* d_ws, size_t ws_size,
                              hipStream_t stream) {
    const float* x    = (const float*)d_in[0];
    const float* h_lo = (const float*)d_in[1];
    const float* bias = (const float*)d_in[2];
    float* out = (float*)d_out;

    dim3 grid(BATCH * CHANS);
    dim3 block(256);
    lwpt_kernel<<<grid, block, 0, stream>>>(x, h_lo, bias, out);
}

// Round 2
// 26.078 us; speedup vs baseline: 1.1947x; 1.1947x over previous
//
#include <hip/hip_runtime.h>
#include <math.h>

#define TLEN 4096
#define LEVELS 4
#define CHANS 32
#define SLOPE 10.0f

// d = hi * (sigmoid(S*(hi-b)) + sigmoid(-S*(hi+b)))
//   = hi * (2 + ea + eb) / ((1+ea)*(1+eb)),  ea=exp(-S*(hi-b)), eb=exp(S*(hi+b))
// clamp exp args to +-30 so ea,eb <= ~1e13 -> product finite, no inf*0 NaN.
__device__ __forceinline__ float sgate(float hi, float b) {
    const float za = fminf(fmaxf(-SLOPE * (hi - b), -30.f), 30.f);
    const float zb = fminf(fmaxf( SLOPE * (hi + b), -30.f), 30.f);
    const float ea = __expf(za);
    const float eb = __expf(zb);
    return hi * (2.f + ea + eb) * __builtin_amdgcn_rcpf((1.f + ea) * (1.f + eb));
}

__global__ __launch_bounds__(256) void lwpt_kernel(
    const float* __restrict__ x, const float* __restrict__ h_lo,
    const float* __restrict__ bias, float* __restrict__ out)
{
    __shared__ float bufA[2048];   // level-1 lo out / level-3 lo out (first 512)
    __shared__ float bufB[1024];   // level-2 lo out

    const int bc  = blockIdx.x;          // row index (b*32 + c)
    const int c   = bc & (CHANS - 1);
    const int tid = threadIdx.x;

    const float* xrow = x   + (size_t)bc * TLEN;
    float*       orow = out + (size_t)bc * TLEN;

    // filters: h_lo is [C, LEVEL, 4] f32 -> one float4 per (c,l)
    const float4 k0v = ((const float4*)h_lo)[c * LEVELS + 0];
    const float4 k1v = ((const float4*)h_lo)[c * LEVELS + 1];
    const float4 k2v = ((const float4*)h_lo)[c * LEVELS + 2];
    const float4 k3v = ((const float4*)h_lo)[c * LEVELS + 3];
    const float b0 = bias[c * LEVELS + 0];
    const float b1 = bias[c * LEVELS + 1];
    const float b2 = bias[c * LEVELS + 2];
    const float b3 = bias[c * LEVELS + 3];

    // ---- Level 1: global -> lo in bufA[0..2048), d1 -> orow[2048..4096)
    {
        const float4* x4 = (const float4*)xrow;
        float in[18];
        #pragma unroll
        for (int k = 0; k < 4; ++k) {
            const float4 v = x4[4 * tid + k];
            in[4*k+0] = v.x; in[4*k+1] = v.y; in[4*k+2] = v.z; in[4*k+3] = v.w;
        }
        const float2 e = *(const float2*)(xrow + ((16 * tid + 16) & (TLEN - 1)));
        in[16] = e.x; in[17] = e.y;

        float lo[8], dd[8];
        #pragma unroll
        for (int j = 0; j < 8; ++j) {
            const float a0 = in[2*j], a1 = in[2*j+1], a2 = in[2*j+2], a3 = in[2*j+3];
            lo[j] = a0*k0v.x + a1*k0v.y + a2*k0v.z + a3*k0v.w;
            const float hi = a0*k0v.w - a1*k0v.z + a2*k0v.y - a3*k0v.x;
            dd[j] = sgate(hi, b0);
        }
        ((float4*)bufA)[2*tid]   = make_float4(lo[0], lo[1], lo[2], lo[3]);
        ((float4*)bufA)[2*tid+1] = make_float4(lo[4], lo[5], lo[6], lo[7]);
        float4* o4 = (float4*)(orow + 2048);
        o4[2*tid]   = make_float4(dd[0], dd[1], dd[2], dd[3]);
        o4[2*tid+1] = make_float4(dd[4], dd[5], dd[6], dd[7]);
    }
    __syncthreads();

    // ---- Level 2: bufA[0..2048) -> lo in bufB[0..1024), d2 -> orow[1024..2048)
    {
        float in[10];
        #pragma unroll
        for (int k = 0; k < 2; ++k) {
            const float4 v = ((const float4*)bufA)[2 * tid + k];
            in[4*k+0] = v.x; in[4*k+1] = v.y; in[4*k+2] = v.z; in[4*k+3] = v.w;
        }
        const float2 e = *(const float2*)(bufA + ((8 * tid + 8) & 2047));
        in[8] = e.x; in[9] = e.y;

        float lo[4], dd[4];
        #pragma unroll
        for (int j = 0; j < 4; ++j) {
            const float a0 = in[2*j], a1 = in[2*j+1], a2 = in[2*j+2], a3 = in[2*j+3];
            lo[j] = a0*k1v.x + a1*k1v.y + a2*k1v.z + a3*k1v.w;
            const float hi = a0*k1v.w - a1*k1v.z + a2*k1v.y - a3*k1v.x;
            dd[j] = sgate(hi, b1);
        }
        ((float4*)bufB)[tid] = make_float4(lo[0], lo[1], lo[2], lo[3]);
        ((float4*)(orow + 1024))[tid] = make_float4(dd[0], dd[1], dd[2], dd[3]);
    }
    __syncthreads();

    // ---- Level 3: bufB[0..1024) -> lo in bufA[0..512), d3 -> orow[512..1024)
    {
        float in[6];
        const float4 v = ((const float4*)bufB)[tid];
        in[0] = v.x; in[1] = v.y; in[2] = v.z; in[3] = v.w;
        const float2 e = *(const float2*)(bufB + ((4 * tid + 4) & 1023));
        in[4] = e.x; in[5] = e.y;

        float lo[2], dd[2];
        #pragma unroll
        for (int j = 0; j < 2; ++j) {
            const float a0 = in[2*j], a1 = in[2*j+1], a2 = in[2*j+2], a3 = in[2*j+3];
            lo[j] = a0*k2v.x + a1*k2v.y + a2*k2v.z + a3*k2v.w;
            const float hi = a0*k2v.w - a1*k2v.z + a2*k2v.y - a3*k2v.x;
            dd[j] = sgate(hi, b2);
        }
        ((float2*)bufA)[tid] = make_float2(lo[0], lo[1]);
        ((float2*)(orow + 512))[tid] = make_float2(dd[0], dd[1]);
    }
    __syncthreads();

    // ---- Level 4: bufA[0..512) -> yl in orow[0..256), d4 -> orow[256..512)
    {
        const float a0 = bufA[2 * tid];
        const float a1 = bufA[2 * tid + 1];
        const float2 e = *(const float2*)(bufA + ((2 * tid + 2) & 511));
        const float a2 = e.x, a3 = e.y;
        const float lo = a0*k3v.x + a1*k3v.y + a2*k3v.z + a3*k3v.w;
        const float hi = a0*k3v.w - a1*k3v.z + a2*k3v.y - a3*k3v.x;
        orow[tid]       = lo;
        orow[256 + tid] = sgate(hi, b3);
    }
}

extern "C" void kernel_launch(void* const* d_in, const int* in_sizes, int n_in,
                              void* d_out, int out_size, void* d_ws, size_t ws_size,
                              hipStream_t stream) {
    const float* x    = (const float*)d_in[0];
    const float* h_lo = (const float*)d_in[1];
    const float* bias = (const float*)d_in[2];
    float* out = (float*)d_out;

    dim3 grid(128 * CHANS);
    dim3 block(256);
    lwpt_kernel<<<grid, block, 0, stream>>>(x, h_lo, bias, out);
}